// Round 8
// baseline (1493.821 us; speedup 1.0000x reference)
//
#include <hip/hip_runtime.h>
#include <hip/hip_bf16.h>

#define RES 64
#define WIDTH 32
#define MODES 8
#define R3 262144            // 64^3
#define TWO_PI_OVER_64 0.09817477042468103f

__device__ __forceinline__ float geluf(float x) {
    // jax.nn.gelu approximate=True: x * sigmoid(1.595769...*(x+0.044715x^3))
    float g = 1.5957691216057308f * (x + 0.044715f * x * x * x);
    return x * __builtin_amdgcn_rcpf(1.0f + __expf(-g));
}

// Compile-time twiddle table: constexpr Taylor cos/sin so the fully-unrolled z-DFT
// folds every twiddle to a literal (v_fmac with inline constant, ZERO LDS reads).
constexpr double tcos_(double x) {
    double r = 1.0, term = 1.0;
    for (int i = 1; i <= 12; i++) { term *= -x * x / ((2.0 * i - 1.0) * (2.0 * i)); r += term; }
    return r;
}
constexpr double tsin_(double x) {
    double r = x, term = x;
    for (int i = 1; i <= 12; i++) { term *= -x * x / ((2.0 * i) * (2.0 * i + 1.0)); r += term; }
    return r;
}
struct Tw64 { float c[64]; float s[64]; };
constexpr Tw64 mkTw() {
    Tw64 t{};
    const double th = 6.283185307179586476925286766559 / 64.0;
    for (int i = 0; i < 64; i++) {
        double a = th * (i <= 32 ? i : i - 64);   // reduce to [-pi, pi] for Taylor
        t.c[i] = (float)tcos_(a);
        t.s[i] = (float)tsin_(a);
    }
    return t;
}
constexpr Tw64 TWT = mkTw();

// ---------------- K0: fc0 pointwise (3 -> 32) ----------------
__global__ void k_fc0(const float* __restrict__ u, const float* __restrict__ w,
                      const float* __restrict__ bias, float* __restrict__ X) {
    __shared__ float ws[96];
    __shared__ float bs[32];
    int t = threadIdx.x;
    if (t < 96) ws[t] = w[t];
    if (t < 32) bs[t] = bias[t];
    __syncthreads();
    size_t s = (size_t)blockIdx.x * 256 + t;     // over B*R3 = 1048576
    int b = (int)(s >> 18);
    size_t p = s & (R3 - 1);
    const float* ub = u + (size_t)b * 3 * R3;
    float u0 = ub[p], u1 = ub[R3 + p], u2 = ub[2 * R3 + p];
    float* xb = X + (size_t)b * 32 * R3;
    #pragma unroll
    for (int o = 0; o < 32; o++) {
        xb[(size_t)o * R3 + p] = bs[o] + u0 * ws[o] + u1 * ws[32 + o] + u2 * ws[64 + o];
    }
}

// ---------------- K1: fused forward DFT over z (64->8) and y (64->16 bins), v2 ----------------
// v2: one row per LANE, direct global b128 reads (no LDS staging, no bank conflicts),
// literal twiddles (constexpr TWT) + z->z+32 even/odd fold: 576 FMA/row, zero LDS in z-loop.
// Block = 4 (b,c,x) planes (one per wave). 2048 blocks, 256 threads.
__global__ void __launch_bounds__(256, 6)
k_fwd_zy(const float* __restrict__ X, float2* __restrict__ S2) {
    int t = threadIdx.x;
    int q = t >> 6, y = t & 63;                  // wave q handles plane bcx0+q, lane = y row
    int bcx0 = blockIdx.x * 4;
    __shared__ float2 zt[4][8][66];              // [plane][kz][y], padded 64->66 (conflict-free)
    __shared__ float2 tw[64];
    if (t < 64) { float s, c; __sincosf(TWO_PI_OVER_64 * t, &s, &c); tw[t] = make_float2(c, s); }

    // ---- stage 1: z-DFT (64 -> 8 bins), one row per thread ----
    const float* row = X + (size_t)(bcx0 + q) * 4096 + (size_t)y * 64;
    float re[8], im[8];
    #pragma unroll
    for (int k = 0; k < 8; k++) { re[k] = 0.f; im[k] = 0.f; }
    #pragma unroll
    for (int zb = 0; zb < 8; zb++) {
        float xa[4], xb4[4];
        *(float4*)xa  = *(const float4*)(row + zb * 4);
        *(float4*)xb4 = *(const float4*)(row + zb * 4 + 32);
        #pragma unroll
        for (int j = 0; j < 4; j++) {
            int z = zb * 4 + j;                  // z in [0,32)
            float sv = xa[j] + xb4[j];           // even-k fold: x[z] + x[z+32]
            float dv = xa[j] - xb4[j];           // odd-k fold:  x[z] - x[z+32]
            #pragma unroll
            for (int k = 0; k < 8; k++) {
                float v = (k & 1) ? dv : sv;
                re[k] += v * TWT.c[(k * z) & 63];   // literal constants after unroll
                im[k] -= v * TWT.s[(k * z) & 63];
            }
        }
    }
    #pragma unroll
    for (int k = 0; k < 8; k++) zt[q][k][y] = make_float2(re[k], im[k]);
    __syncthreads();

    // ---- stage 2: y-DFT (64 -> 16 bins), 2 outputs per thread ----
    int l = t & 63;
    int jy = l >> 2, kp = l & 3;
    int f = jy < 8 ? jy : 48 + jy;
    int k0 = kp * 2;
    float re0 = 0.f, im0 = 0.f, re1 = 0.f, im1 = 0.f;
    #pragma unroll 8
    for (int yy = 0; yy < 64; yy++) {
        float2 w = tw[(f * yy) & 63];
        float2 v0 = zt[q][k0][yy];
        float2 v1 = zt[q][k0 + 1][yy];
        re0 += v0.x * w.x + v0.y * w.y;          // * conj(w)
        im0 += v0.y * w.x - v0.x * w.y;
        re1 += v1.x * w.x + v1.y * w.y;
        im1 += v1.y * w.x - v1.x * w.y;
    }
    float2* dst = S2 + (size_t)(bcx0 + q) * 128 + jy * 8 + k0;
    dst[0] = make_float2(re0, im0);
    dst[1] = make_float2(re1, im1);
}

// ---------------- K2: forward DFT over x: 64 -> 16 bins ----------------
// block per (bc, kz); 1024 blocks, 256 threads (jx16 x jy16)
__global__ void k_fwd_x(const float2* __restrict__ S2, float2* __restrict__ S3) {
    int bc = blockIdx.x >> 3, kz = blockIdx.x & 7;
    int t = threadIdx.x;
    __shared__ float2 in[64 * 16];  // [x][jy]
    __shared__ float2 tw[64];
    if (t < 64) { float s, c; __sincosf(TWO_PI_OVER_64 * t, &s, &c); tw[t] = make_float2(c, s); }
    #pragma unroll
    for (int i = 0; i < 4; i++) {
        int e = t + 256 * i;        // e = x*16 + jy
        in[e] = S2[((size_t)bc * 1024 + e) * 8 + kz];
    }
    __syncthreads();
    int jx = t >> 4, jy = t & 15;
    int f = jx < 8 ? jx : 48 + jx;
    float re = 0.f, im = 0.f;
    for (int x = 0; x < 64; x++) {
        float2 v = in[x * 16 + jy];
        float2 w = tw[(f * x) & 63];
        re += v.x * w.x + v.y * w.y;
        im += v.y * w.x - v.x * w.y;
    }
    // S3 layout: [b][i][mode], mode = (jx*16+jy)*8 + kz
    S3[(size_t)bc * 2048 + (size_t)t * 8 + kz] = make_float2(re, im);
}

// ---------------- K3: spectral multiply, two m3-modes per block ----------------
// out[b,o,mode] = sum_i in[b,i,mode]*W[i,o]; 1024 blocks, 128 threads (b4 x o32)
__global__ void k_specmul(const float2* __restrict__ S3, const float* __restrict__ spec_w,
                          float2* __restrict__ S4, int layer) {
    int mp = blockIdx.x;                 // mode pair
    int t = threadIdx.x;
    int jxy = mp >> 2;                   // jx*16+jy
    int kz0 = (mp & 3) * 2;
    int jy = jxy & 15, jx = jxy >> 4;
    int corner = (jx >= 8 ? 1 : 0) + (jy >= 8 ? 2 : 0);
    int m1 = jx & 7, m2 = jy & 7;
    int mode0 = jxy * 8 + kz0;
    __shared__ float4 W4[1024];          // [i][o] -> (re0,im0,re1,im1)
    __shared__ float2 inb[2][128];       // [mode][b*32+i]
    const float* wbase = spec_w + (size_t)layer * 4194304 + (size_t)corner * 1048576
                       + m1 * 128 + m2 * 16 + kz0 * 2;
    #pragma unroll
    for (int j = 0; j < 8; j++) {
        int e = t + 128 * j;    // i*32 + o
        int i = e >> 5, o = e & 31;
        W4[e] = *(const float4*)(wbase + (size_t)i * 32768 + (size_t)o * 1024);
    }
    inb[0][t] = S3[(size_t)t * 2048 + mode0];
    inb[1][t] = S3[(size_t)t * 2048 + mode0 + 1];
    __syncthreads();
    int b = t >> 5, o = t & 31;
    float re0 = 0.f, im0 = 0.f, re1 = 0.f, im1 = 0.f;
    #pragma unroll 8
    for (int i = 0; i < 32; i++) {
        float2 a0 = inb[0][b * 32 + i];
        float2 a1 = inb[1][b * 32 + i];
        float4 w = W4[i * 32 + o];
        re0 += a0.x * w.x - a0.y * w.y;
        im0 += a0.x * w.y + a0.y * w.x;
        re1 += a1.x * w.z - a1.y * w.w;
        im1 += a1.x * w.w + a1.y * w.z;
    }
    S4[(size_t)(b * 32 + o) * 2048 + mode0]     = make_float2(re0, im0);
    S4[(size_t)(b * 32 + o) * 2048 + mode0 + 1] = make_float2(re1, im1);
}

// ---------------- K4: inverse DFT over x: 16 bins -> 64 ----------------
// block per (bo, kz); 1024 blocks, 256 threads
__global__ void k_inv_x(const float2* __restrict__ S4, float2* __restrict__ S5) {
    int bo = blockIdx.x >> 3, kz = blockIdx.x & 7;
    int t = threadIdx.x;
    __shared__ float2 in[256];   // [jx][jy]
    __shared__ float2 tw[64];
    if (t < 64) { float s, c; __sincosf(TWO_PI_OVER_64 * t, &s, &c); tw[t] = make_float2(c, s); }
    in[t] = S4[(size_t)bo * 2048 + (size_t)t * 8 + kz];
    __syncthreads();
    int x = t & 63, g = t >> 6;
    #pragma unroll
    for (int m = 0; m < 4; m++) {
        int jy = g + 4 * m;
        float re = 0.f, im = 0.f;
        #pragma unroll
        for (int jx = 0; jx < 16; jx++) {
            int f = jx < 8 ? jx : 48 + jx;
            float2 v = in[jx * 16 + jy];
            float2 w = tw[(f * x) & 63];
            re += v.x * w.x - v.y * w.y;   // e^{+i theta}
            im += v.x * w.y + v.y * w.x;
        }
        // S5 layout [bo][x][jy][kz]
        S5[((size_t)bo * 64 + x) * 128 + jy * 8 + kz] = make_float2(re, im);
    }
}

// ---------------- K5: fused inverse-y + inverse-z DFT + pointwise + add + gelu (IN-PLACE on X) ----
// v6: v4's register-resident S5 row, spill-proofed CORRECTLY this time.
// History: v4 (LDS 10.75K) -> allocator chased 8 waves/EU, VGPR 64, sr spilled (FETCH 407MB).
// v5's LDS pad was DCE'd (store under never-taken branch, never read -> removable; LDS stayed
// 10752). v6 uses the direct tool: amdgpu_waves_per_eu(4,4) pins the regalloc occupancy
// target at 4 waves/EU (VGPR budget 128 vs ~85 demand -> no spill, nothing to gain by
// squeezing), PLUS the LDS governor made un-removable via an unconditional VOLATILE store
// (volatile accesses cannot be DCE'd). Pre-commit: if VGPR is still 64, revert to r5-v3.
__global__ void __launch_bounds__(256)
__attribute__((amdgpu_waves_per_eu(4, 4)))
k_inv_yz_pw(const float2* __restrict__ S5, const float* __restrict__ w_pw,
            const float* __restrict__ b_pw, float* __restrict__ X,
            int layer, int do_gelu) {
    int blk = blockIdx.x;
    int yg = blk & 3, x = (blk >> 2) & 63, b = blk >> 8;
    int t = threadIdx.x;
    __shared__ float2 st[256];         // [o][k]        2 KB
    __shared__ float xt[2048];         // [c][z]        8 KB
    __shared__ float2 tw[64];          //               0.5 KB
    __shared__ float ldspad[6400];     // 25.6 KB occupancy governor -> total 36.35 KB:
                                       // LDS caps at 4 blocks/CU even if the attribute is ignored
    ((volatile float*)ldspad)[t] = 0.f;    // volatile: cannot be DCE'd; keeps ldspad allocated
    if (t < 64) { float s, c; __sincosf(TWO_PI_OVER_64 * t, &s, &c); tw[t] = make_float2(c, s); }

    int oA = t >> 3, kA = t & 7;       // stage-A role: unique (o,k) per thread
    // register-resident S5 row: sr[jy] = S5[((b*32+oA)*64+x)*128 + jy*8 + kA], const over yi
    float2 sr[16];
    const float2* s5p = S5 + ((size_t)(b * 32 + oA) * 64 + x) * 128 + kA;
    #pragma unroll
    for (int jy = 0; jy < 16; jy++) sr[jy] = s5p[jy * 8];

    int z = t & 63, og = t >> 6;       // stage-C roles (og wave-uniform)
    int og8 = og * 8;
    int og8u = __builtin_amdgcn_readfirstlane(og8);   // SGPR: uniform weight row base
    const float* wl = w_pw + layer * 1024 + og8u;     // uniform -> s_load
    const float* bl = b_pw + layer * 32 + og8u;       // uniform -> s_load
    float bt0 = bl[0], bt1 = bl[1], bt2 = bl[2], bt3 = bl[3];
    float bt4 = bl[4], bt5 = bl[5], bt6 = bl[6], bt7 = bl[7];
    // named z-twiddle registers (k=0 twiddle is (1,0): handled inline)
    float2 tz1, tz2, tz3, tz4, tz5, tz6, tz7;
    {   // tw needs to be initialized before these reads
        __syncthreads();
        tz1 = tw[z];
        tz2 = tw[(2 * z) & 63];
        tz3 = tw[(3 * z) & 63];
        tz4 = tw[(4 * z) & 63];
        tz5 = tw[(5 * z) & 63];
        tz6 = tw[(6 * z) & 63];
        tz7 = tw[(7 * z) & 63];
    }
    const float inv_n = 1.0f / 262144.0f;

    size_t base0 = (size_t)b * 8388608 + (size_t)(x * 64 + yg * 16) * 64;

    for (int yi = 0; yi < 16; yi++) {
        int y = yg * 16 + yi;
        size_t base = base0 + (size_t)yi * 64;
        // stage B: load X column for this y -> xt (loads overlap stage A's register math)
        #pragma unroll
        for (int i = 0; i < 8; i++) {
            int e = t + 256 * i;   // c*64 + z
            xt[e] = X[base + (size_t)(e >> 6) * R3 + (e & 63)];
        }
        // stage A: inverse-y from REGISTERS (sr) -> st[t]; tw reads are uniform broadcasts
        {
            float re = 0.f, im = 0.f;
            #pragma unroll
            for (int jy = 0; jy < 16; jy++) {
                int f = jy < 8 ? jy : 48 + jy;
                float2 w = tw[(f * y) & 63];
                re += sr[jy].x * w.x - sr[jy].y * w.y;   // e^{+i theta}
                im += sr[jy].x * w.y + sr[jy].y * w.x;
            }
            st[t] = make_float2(re, im);
        }
        __syncthreads();
        // stage C init: inverse-z (pocketfft c2r: Re of k=0, 2x k=1..7); st reads are
        // wave-uniform b64 broadcasts (og wave-uniform). All values named scalars.
#define INVZ_S(o) (st[(o) * 8 + 0].x \
        + 2.f * (st[(o) * 8 + 1].x * tz1.x - st[(o) * 8 + 1].y * tz1.y) \
        + 2.f * (st[(o) * 8 + 2].x * tz2.x - st[(o) * 8 + 2].y * tz2.y) \
        + 2.f * (st[(o) * 8 + 3].x * tz3.x - st[(o) * 8 + 3].y * tz3.y) \
        + 2.f * (st[(o) * 8 + 4].x * tz4.x - st[(o) * 8 + 4].y * tz4.y) \
        + 2.f * (st[(o) * 8 + 5].x * tz5.x - st[(o) * 8 + 5].y * tz5.y) \
        + 2.f * (st[(o) * 8 + 6].x * tz6.x - st[(o) * 8 + 6].y * tz6.y) \
        + 2.f * (st[(o) * 8 + 7].x * tz7.x - st[(o) * 8 + 7].y * tz7.y))
        float acc0 = bt0 + INVZ_S(og8 + 0) * inv_n;
        float acc1 = bt1 + INVZ_S(og8 + 1) * inv_n;
        float acc2 = bt2 + INVZ_S(og8 + 2) * inv_n;
        float acc3 = bt3 + INVZ_S(og8 + 3) * inv_n;
        float acc4 = bt4 + INVZ_S(og8 + 4) * inv_n;
        float acc5 = bt5 + INVZ_S(og8 + 5) * inv_n;
        float acc6 = bt6 + INVZ_S(og8 + 6) * inv_n;
        float acc7 = bt7 + INVZ_S(og8 + 7) * inv_n;
#undef INVZ_S
        // stage C main: c-outer pointwise; xt once per c; weights via SMEM (s_load).
        #pragma unroll 4
        for (int c = 0; c < 32; c++) {
            float xc = xt[c * 64 + z];
            const float* wr = wl + c * 32;                 // uniform: s_load_dwordx8
            float w0 = wr[0], w1 = wr[1], w2 = wr[2], w3 = wr[3];
            float w4 = wr[4], w5 = wr[5], w6 = wr[6], w7 = wr[7];
            acc0 += xc * w0; acc1 += xc * w1; acc2 += xc * w2; acc3 += xc * w3;
            acc4 += xc * w4; acc5 += xc * w5; acc6 += xc * w6; acc7 += xc * w7;
        }
        __syncthreads();   // all st/xt reads done before next iteration overwrites
        float r;
        r = do_gelu ? geluf(acc0) : acc0; X[base + (size_t)(og8 + 0) * R3 + z] = r;
        r = do_gelu ? geluf(acc1) : acc1; X[base + (size_t)(og8 + 1) * R3 + z] = r;
        r = do_gelu ? geluf(acc2) : acc2; X[base + (size_t)(og8 + 2) * R3 + z] = r;
        r = do_gelu ? geluf(acc3) : acc3; X[base + (size_t)(og8 + 3) * R3 + z] = r;
        r = do_gelu ? geluf(acc4) : acc4; X[base + (size_t)(og8 + 4) * R3 + z] = r;
        r = do_gelu ? geluf(acc5) : acc5; X[base + (size_t)(og8 + 5) * R3 + z] = r;
        r = do_gelu ? geluf(acc6) : acc6; X[base + (size_t)(og8 + 6) * R3 + z] = r;
        r = do_gelu ? geluf(acc7) : acc7; X[base + (size_t)(og8 + 7) * R3 + z] = r;
    }
}

// ---------------- K6: head v5 — MFMA fc1 (hi/lo bf16 split) + fp32 gelu/fc2 + DPP reduce ----
// 4096 blocks, 256 threads (4 waves), 256 sites/block. Per wave-iteration: 16 sites.
typedef short bf16x8_t __attribute__((ext_vector_type(8)));
typedef float f32x4_t __attribute__((ext_vector_type(4)));

__device__ __forceinline__ float dpp_add16(float v) {
    int i;
    i = __builtin_amdgcn_update_dpp(0, __builtin_bit_cast(int, v), 0xB1, 0xF, 0xF, true);   // quad_perm xor1
    v += __builtin_bit_cast(float, i);
    i = __builtin_amdgcn_update_dpp(0, __builtin_bit_cast(int, v), 0x4E, 0xF, 0xF, true);   // quad_perm xor2
    v += __builtin_bit_cast(float, i);
    i = __builtin_amdgcn_update_dpp(0, __builtin_bit_cast(int, v), 0x141, 0xF, 0xF, true);  // row_half_mirror
    v += __builtin_bit_cast(float, i);
    i = __builtin_amdgcn_update_dpp(0, __builtin_bit_cast(int, v), 0x140, 0xF, 0xF, true);  // row_mirror
    v += __builtin_bit_cast(float, i);
    return v;
}

__global__ void __launch_bounds__(256, 2)
k_head(const float* __restrict__ X, const float* __restrict__ w1,
       const float* __restrict__ b1, const float* __restrict__ w2,
       const float* __restrict__ b2, float* __restrict__ tau_out) {
    int t = threadIdx.x;
    int lane = t & 63;
    int wv = t >> 6;                       // wave 0..3
    int m = lane & 15;                     // A-row-in-frag / D-col(h) / B-col index
    int g = lane >> 4;                     // k-group; D rows (sites) = g*4 + r
    size_t sblock = (size_t)blockIdx.x * 256;
    int b = (int)(sblock >> 18);
    size_t pblock = sblock & (R3 - 1);     // 256-aligned; R3 % 256 == 0, no b crossing
    const float* xb = X + (size_t)b * 8388608 + pblock;

    // ---- prologue (loop-invariant): B-frags hi/lo for 8 h-tiles ----
    bf16x8_t Bhi[8], Blo[8];
    #pragma unroll
    for (int tt = 0; tt < 8; tt++) {
        #pragma unroll
        for (int j = 0; j < 8; j++) {
            float w = w1[(g * 8 + j) * 128 + tt * 16 + m];
            unsigned bits = __builtin_bit_cast(unsigned, w);
            float hf = __builtin_bit_cast(float, bits & 0xFFFF0000u);
            float lof = w - hf;                                   // exact
            unsigned lb = __builtin_bit_cast(unsigned, lof);
            Bhi[tt][j] = (short)(bits >> 16);
            Blo[tt][j] = (short)(lb >> 16);
        }
    }
    // per-lane fc2 weights (h = 16*tt + m), fc1 bias, fc2 bias
    float w2r[8][6];
    #pragma unroll
    for (int tt = 0; tt < 8; tt++)
        #pragma unroll
        for (int o = 0; o < 6; o++) w2r[tt][o] = w2[(tt * 16 + m) * 6 + o];
    float b1r[8];
    #pragma unroll
    for (int tt = 0; tt < 8; tt++) b1r[tt] = b1[tt * 16 + m];
    float b2m = b2[m < 6 ? m : 0];

    for (int it = 0; it < 4; it++) {
        int s16 = wv * 64 + it * 16;       // site base (within block) for this 16-site tile
        // ---- A-frags: lane holds X[c = g*8+j][site = s16 + m], hi/lo split ----
        bf16x8_t Ahi, Alo;
        #pragma unroll
        for (int j = 0; j < 8; j++) {
            float xv = xb[(size_t)(g * 8 + j) * R3 + s16 + m];
            unsigned bits = __builtin_bit_cast(unsigned, xv);
            float hf = __builtin_bit_cast(float, bits & 0xFFFF0000u);
            float lof = xv - hf;                                  // exact
            unsigned lb = __builtin_bit_cast(unsigned, lof);
            Ahi[j] = (short)(bits >> 16);
            Alo[j] = (short)(lb >> 16);
        }
        // ---- fc1 (one MFMA contracts full K=32) + gelu + fc2 partials ----
        float p0[6] = {0.f, 0.f, 0.f, 0.f, 0.f, 0.f};
        float p1[6] = {0.f, 0.f, 0.f, 0.f, 0.f, 0.f};
        float p2[6] = {0.f, 0.f, 0.f, 0.f, 0.f, 0.f};
        float p3[6] = {0.f, 0.f, 0.f, 0.f, 0.f, 0.f};
        #pragma unroll
        for (int tt = 0; tt < 8; tt++) {
            f32x4_t d = {0.f, 0.f, 0.f, 0.f};
            d = __builtin_amdgcn_mfma_f32_16x16x32_bf16(Ahi, Bhi[tt], d, 0, 0, 0);
            d = __builtin_amdgcn_mfma_f32_16x16x32_bf16(Ahi, Blo[tt], d, 0, 0, 0);
            d = __builtin_amdgcn_mfma_f32_16x16x32_bf16(Alo, Bhi[tt], d, 0, 0, 0);
            // d[r] = fc1[site = s16 + g*4 + r][h = 16*tt + m]
            float a0 = geluf(d[0] + b1r[tt]);
            float a1 = geluf(d[1] + b1r[tt]);
            float a2 = geluf(d[2] + b1r[tt]);
            float a3 = geluf(d[3] + b1r[tt]);
            #pragma unroll
            for (int o = 0; o < 6; o++) {
                float w = w2r[tt][o];
                p0[o] += a0 * w; p1[o] += a1 * w; p2[o] += a2 * w; p3[o] += a3 * w;
            }
        }
        // ---- reduce over the 16 m-lanes (VALU DPP butterfly), select o = m, store ----
        float q0 = 0.f, q1 = 0.f, q2 = 0.f, q3 = 0.f;
        #pragma unroll
        for (int o = 0; o < 6; o++) {
            float r0 = dpp_add16(p0[o]);
            float r1 = dpp_add16(p1[o]);
            float r2 = dpp_add16(p2[o]);
            float r3 = dpp_add16(p3[o]);
            q0 = (m == o) ? r0 : q0;
            q1 = (m == o) ? r1 : q1;
            q2 = (m == o) ? r2 : q2;
            q3 = (m == o) ? r3 : q3;
        }
        if (m < 6) {
            float4 vv = make_float4(q0 + b2m, q1 + b2m, q2 + b2m, q3 + b2m);
            *(float4*)(tau_out + (size_t)b * 6 * R3 + (size_t)m * R3 + pblock + s16 + g * 4) = vv;
        }
    }
}

// ---------------- K7: NS hard core + combine ----------------
// 12288 blocks, 256 threads; s over B*3*R3
__global__ void k_hard(const float* __restrict__ u, const float* __restrict__ tau,
                       float* __restrict__ out0) {
    size_t s = (size_t)blockIdx.x * 256 + threadIdx.x;
    int bi = (int)(s >> 18);
    int b = bi / 3, i = bi % 3;
    size_t p = s & (R3 - 1);
    int x = (int)(p >> 12), y = ((int)p >> 6) & 63, z = (int)p & 63;
    const float dx = TWO_PI_OVER_64;
    const float inv2dx = 1.0f / (2.0f * dx);
    const float invdx2 = 1.0f / (dx * dx);
    const float* ub = u + (size_t)b * 3 * R3;
    const float* ui = ub + (size_t)i * R3;
    int xp = (x + 1) & 63, xm = (x + 63) & 63;
    int yp = (y + 1) & 63, ym = (y + 63) & 63;
    int zp = (z + 1) & 63, zm = (z + 63) & 63;
    float c0 = ui[p];
    float upx = ui[((size_t)xp << 12) | (y << 6) | z], umx = ui[((size_t)xm << 12) | (y << 6) | z];
    float upy = ui[((size_t)x << 12) | (yp << 6) | z], umy = ui[((size_t)x << 12) | (ym << 6) | z];
    float upz = ui[((size_t)x << 12) | (y << 6) | zp], umz = ui[((size_t)x << 12) | (y << 6) | zm];
    float u0c = ub[p], u1c = ub[R3 + p], u2c = ub[2 * R3 + p];
    float conv = -(u0c * (upx - umx) + u1c * (upy - umy) + u2c * (upz - umz)) * inv2dx;
    float diff = (upx + umx + upy + umy + upz + umz - 6.0f * c0) * invdx2;
    float tauv = tau[(size_t)b * 6 * R3 + (size_t)i * R3 + p];
    out0[s] = conv + 0.000185f * diff + 0.001f * tauv;
}

extern "C" void kernel_launch(void* const* d_in, const int* in_sizes, int n_in,
                              void* d_out, int out_size, void* d_ws, size_t ws_size,
                              hipStream_t stream) {
    const float* u      = (const float*)d_in[0];
    const float* fc0_w  = (const float*)d_in[1];
    const float* fc0_b  = (const float*)d_in[2];
    const float* spec_w = (const float*)d_in[3];
    const float* w_pw   = (const float*)d_in[4];
    const float* b_pw   = (const float*)d_in[5];
    const float* fc1_w  = (const float*)d_in[6];
    const float* fc1_b  = (const float*)d_in[7];
    const float* fc2_w  = (const float*)d_in[8];
    const float* fc2_b  = (const float*)d_in[9];
    float* out = (float*)d_out;

    // d_ws: only the activation tensor X (B*32*64^3 floats = 128 MiB), updated in place.
    float* X = (float*)d_ws;

    // Spectral stage buffers live in d_out's dead space (20 MiB of 36 MiB total).
    // All are dead before k_head/k_hard overwrite tau/du at the end.
    float2* S2 = (float2*)(out);                // 1048576 float2 =  8 MiB, floats [0, 2097152)
    float2* S3 = (float2*)(out + 2097152);      //  262144 float2 =  2 MiB
    float2* S4 = (float2*)(out + 2621440);      //  262144 float2 =  2 MiB
    float2* S5 = (float2*)(out + 3145728);      // 1048576 float2 =  8 MiB, ends at float 5242880

    k_fc0<<<4096, 256, 0, stream>>>(u, fc0_w, fc0_b, X);

    for (int l = 0; l < 4; l++) {
        k_fwd_zy<<<2048, 256, 0, stream>>>(X, S2);
        k_fwd_x<<<1024, 256, 0, stream>>>(S2, S3);
        k_specmul<<<1024, 128, 0, stream>>>(S3, spec_w, S4, l);
        k_inv_x<<<1024, 256, 0, stream>>>(S4, S5);
        k_inv_yz_pw<<<1024, 256, 0, stream>>>(S5, w_pw, b_pw, X, l, (l < 3) ? 1 : 0);
    }

    float* tau_out = out + (size_t)4 * 3 * R3;   // second output section (offset 3145728)
    k_head<<<4096, 256, 0, stream>>>(X, fc1_w, fc1_b, fc2_w, fc2_b, tau_out);
    k_hard<<<12288, 256, 0, stream>>>(u, tau_out, out);
}

// Round 9
// 1077.637 us; speedup vs baseline: 1.3862x; 1.3862x over previous
//
#include <hip/hip_runtime.h>
#include <hip/hip_bf16.h>

#define RES 64
#define WIDTH 32
#define MODES 8
#define R3 262144            // 64^3
#define TWO_PI_OVER_64 0.09817477042468103f

__device__ __forceinline__ float geluf(float x) {
    // jax.nn.gelu approximate=True: x * sigmoid(1.595769...*(x+0.044715x^3))
    float g = 1.5957691216057308f * (x + 0.044715f * x * x * x);
    return x * __builtin_amdgcn_rcpf(1.0f + __expf(-g));
}

// Compile-time twiddle table: constexpr Taylor cos/sin so the fully-unrolled z-DFT
// folds every twiddle to a literal (v_fmac with inline constant, ZERO LDS reads).
constexpr double tcos_(double x) {
    double r = 1.0, term = 1.0;
    for (int i = 1; i <= 12; i++) { term *= -x * x / ((2.0 * i - 1.0) * (2.0 * i)); r += term; }
    return r;
}
constexpr double tsin_(double x) {
    double r = x, term = x;
    for (int i = 1; i <= 12; i++) { term *= -x * x / ((2.0 * i) * (2.0 * i + 1.0)); r += term; }
    return r;
}
struct Tw64 { float c[64]; float s[64]; };
constexpr Tw64 mkTw() {
    Tw64 t{};
    const double th = 6.283185307179586476925286766559 / 64.0;
    for (int i = 0; i < 64; i++) {
        double a = th * (i <= 32 ? i : i - 64);   // reduce to [-pi, pi] for Taylor
        t.c[i] = (float)tcos_(a);
        t.s[i] = (float)tsin_(a);
    }
    return t;
}
constexpr Tw64 TWT = mkTw();

// ---------------- K0: fc0 pointwise (3 -> 32) ----------------
__global__ void k_fc0(const float* __restrict__ u, const float* __restrict__ w,
                      const float* __restrict__ bias, float* __restrict__ X) {
    __shared__ float ws[96];
    __shared__ float bs[32];
    int t = threadIdx.x;
    if (t < 96) ws[t] = w[t];
    if (t < 32) bs[t] = bias[t];
    __syncthreads();
    size_t s = (size_t)blockIdx.x * 256 + t;     // over B*R3 = 1048576
    int b = (int)(s >> 18);
    size_t p = s & (R3 - 1);
    const float* ub = u + (size_t)b * 3 * R3;
    float u0 = ub[p], u1 = ub[R3 + p], u2 = ub[2 * R3 + p];
    float* xb = X + (size_t)b * 32 * R3;
    #pragma unroll
    for (int o = 0; o < 32; o++) {
        xb[(size_t)o * R3 + p] = bs[o] + u0 * ws[o] + u1 * ws[32 + o] + u2 * ws[64 + o];
    }
}

// ---------------- K1: fused forward DFT over z (64->8) and y (64->16 bins), v2 ----------------
// v2: one row per LANE, direct global b128 reads (no LDS staging, no bank conflicts),
// literal twiddles (constexpr TWT) + z->z+32 even/odd fold: 576 FMA/row, zero LDS in z-loop.
// Block = 4 (b,c,x) planes (one per wave). 2048 blocks, 256 threads.
__global__ void __launch_bounds__(256, 6)
k_fwd_zy(const float* __restrict__ X, float2* __restrict__ S2) {
    int t = threadIdx.x;
    int q = t >> 6, y = t & 63;                  // wave q handles plane bcx0+q, lane = y row
    int bcx0 = blockIdx.x * 4;
    __shared__ float2 zt[4][8][66];              // [plane][kz][y], padded 64->66 (conflict-free)
    __shared__ float2 tw[64];
    if (t < 64) { float s, c; __sincosf(TWO_PI_OVER_64 * t, &s, &c); tw[t] = make_float2(c, s); }

    // ---- stage 1: z-DFT (64 -> 8 bins), one row per thread ----
    const float* row = X + (size_t)(bcx0 + q) * 4096 + (size_t)y * 64;
    float re[8], im[8];
    #pragma unroll
    for (int k = 0; k < 8; k++) { re[k] = 0.f; im[k] = 0.f; }
    #pragma unroll
    for (int zb = 0; zb < 8; zb++) {
        float xa[4], xb4[4];
        *(float4*)xa  = *(const float4*)(row + zb * 4);
        *(float4*)xb4 = *(const float4*)(row + zb * 4 + 32);
        #pragma unroll
        for (int j = 0; j < 4; j++) {
            int z = zb * 4 + j;                  // z in [0,32)
            float sv = xa[j] + xb4[j];           // even-k fold: x[z] + x[z+32]
            float dv = xa[j] - xb4[j];           // odd-k fold:  x[z] - x[z+32]
            #pragma unroll
            for (int k = 0; k < 8; k++) {
                float v = (k & 1) ? dv : sv;
                re[k] += v * TWT.c[(k * z) & 63];   // literal constants after unroll
                im[k] -= v * TWT.s[(k * z) & 63];
            }
        }
    }
    #pragma unroll
    for (int k = 0; k < 8; k++) zt[q][k][y] = make_float2(re[k], im[k]);
    __syncthreads();

    // ---- stage 2: y-DFT (64 -> 16 bins), 2 outputs per thread ----
    int l = t & 63;
    int jy = l >> 2, kp = l & 3;
    int f = jy < 8 ? jy : 48 + jy;
    int k0 = kp * 2;
    float re0 = 0.f, im0 = 0.f, re1 = 0.f, im1 = 0.f;
    #pragma unroll 8
    for (int yy = 0; yy < 64; yy++) {
        float2 w = tw[(f * yy) & 63];
        float2 v0 = zt[q][k0][yy];
        float2 v1 = zt[q][k0 + 1][yy];
        re0 += v0.x * w.x + v0.y * w.y;          // * conj(w)
        im0 += v0.y * w.x - v0.x * w.y;
        re1 += v1.x * w.x + v1.y * w.y;
        im1 += v1.y * w.x - v1.x * w.y;
    }
    float2* dst = S2 + (size_t)(bcx0 + q) * 128 + jy * 8 + k0;
    dst[0] = make_float2(re0, im0);
    dst[1] = make_float2(re1, im1);
}

// ---------------- K2: forward DFT over x: 64 -> 16 bins ----------------
// block per (bc, kz); 1024 blocks, 256 threads (jx16 x jy16)
__global__ void k_fwd_x(const float2* __restrict__ S2, float2* __restrict__ S3) {
    int bc = blockIdx.x >> 3, kz = blockIdx.x & 7;
    int t = threadIdx.x;
    __shared__ float2 in[64 * 16];  // [x][jy]
    __shared__ float2 tw[64];
    if (t < 64) { float s, c; __sincosf(TWO_PI_OVER_64 * t, &s, &c); tw[t] = make_float2(c, s); }
    #pragma unroll
    for (int i = 0; i < 4; i++) {
        int e = t + 256 * i;        // e = x*16 + jy
        in[e] = S2[((size_t)bc * 1024 + e) * 8 + kz];
    }
    __syncthreads();
    int jx = t >> 4, jy = t & 15;
    int f = jx < 8 ? jx : 48 + jx;
    float re = 0.f, im = 0.f;
    for (int x = 0; x < 64; x++) {
        float2 v = in[x * 16 + jy];
        float2 w = tw[(f * x) & 63];
        re += v.x * w.x + v.y * w.y;
        im += v.y * w.x - v.x * w.y;
    }
    // S3 layout: [b][i][mode], mode = (jx*16+jy)*8 + kz
    S3[(size_t)bc * 2048 + (size_t)t * 8 + kz] = make_float2(re, im);
}

// ---------------- K3: spectral multiply, two m3-modes per block ----------------
// out[b,o,mode] = sum_i in[b,i,mode]*W[i,o]; 1024 blocks, 128 threads (b4 x o32)
__global__ void k_specmul(const float2* __restrict__ S3, const float* __restrict__ spec_w,
                          float2* __restrict__ S4, int layer) {
    int mp = blockIdx.x;                 // mode pair
    int t = threadIdx.x;
    int jxy = mp >> 2;                   // jx*16+jy
    int kz0 = (mp & 3) * 2;
    int jy = jxy & 15, jx = jxy >> 4;
    int corner = (jx >= 8 ? 1 : 0) + (jy >= 8 ? 2 : 0);
    int m1 = jx & 7, m2 = jy & 7;
    int mode0 = jxy * 8 + kz0;
    __shared__ float4 W4[1024];          // [i][o] -> (re0,im0,re1,im1)
    __shared__ float2 inb[2][128];       // [mode][b*32+i]
    const float* wbase = spec_w + (size_t)layer * 4194304 + (size_t)corner * 1048576
                       + m1 * 128 + m2 * 16 + kz0 * 2;
    #pragma unroll
    for (int j = 0; j < 8; j++) {
        int e = t + 128 * j;    // i*32 + o
        int i = e >> 5, o = e & 31;
        W4[e] = *(const float4*)(wbase + (size_t)i * 32768 + (size_t)o * 1024);
    }
    inb[0][t] = S3[(size_t)t * 2048 + mode0];
    inb[1][t] = S3[(size_t)t * 2048 + mode0 + 1];
    __syncthreads();
    int b = t >> 5, o = t & 31;
    float re0 = 0.f, im0 = 0.f, re1 = 0.f, im1 = 0.f;
    #pragma unroll 8
    for (int i = 0; i < 32; i++) {
        float2 a0 = inb[0][b * 32 + i];
        float2 a1 = inb[1][b * 32 + i];
        float4 w = W4[i * 32 + o];
        re0 += a0.x * w.x - a0.y * w.y;
        im0 += a0.x * w.y + a0.y * w.x;
        re1 += a1.x * w.z - a1.y * w.w;
        im1 += a1.x * w.w + a1.y * w.z;
    }
    S4[(size_t)(b * 32 + o) * 2048 + mode0]     = make_float2(re0, im0);
    S4[(size_t)(b * 32 + o) * 2048 + mode0 + 1] = make_float2(re1, im1);
}

// ---------------- K4: inverse DFT over x: 16 bins -> 64 ----------------
// block per (bo, kz); 1024 blocks, 256 threads
__global__ void k_inv_x(const float2* __restrict__ S4, float2* __restrict__ S5) {
    int bo = blockIdx.x >> 3, kz = blockIdx.x & 7;
    int t = threadIdx.x;
    __shared__ float2 in[256];   // [jx][jy]
    __shared__ float2 tw[64];
    if (t < 64) { float s, c; __sincosf(TWO_PI_OVER_64 * t, &s, &c); tw[t] = make_float2(c, s); }
    in[t] = S4[(size_t)bo * 2048 + (size_t)t * 8 + kz];
    __syncthreads();
    int x = t & 63, g = t >> 6;
    #pragma unroll
    for (int m = 0; m < 4; m++) {
        int jy = g + 4 * m;
        float re = 0.f, im = 0.f;
        #pragma unroll
        for (int jx = 0; jx < 16; jx++) {
            int f = jx < 8 ? jx : 48 + jx;
            float2 v = in[jx * 16 + jy];
            float2 w = tw[(f * x) & 63];
            re += v.x * w.x - v.y * w.y;   // e^{+i theta}
            im += v.x * w.y + v.y * w.x;
        }
        // S5 layout [bo][x][jy][kz]
        S5[((size_t)bo * 64 + x) * 128 + jy * 8 + kz] = make_float2(re, im);
    }
}

// ---------------- K5: fused inverse-y + inverse-z DFT + pointwise + add + gelu (IN-PLACE on X) ----
// v7 = round-5 v3 REVERT (verified 136 us/dispatch) + grid split 1024->2048 blocks (8 y/block).
// History: v4/v5/v6 all tried register-resident S5 rows; the allocator spilled the 32-dword
// array to scratch in every variant (VGPR pinned at 64, FETCH 337-407 MB) despite LDS governor
// + waves_per_eu. Conclusion: structural — abandon that path. v3's s5s-in-LDS is the verified
// fast form. The grid split targets v3's 25% occupancy (1024 blocks / 256 CUs, 3-resident):
// 2048 blocks double machine fill; s5s staging amortized over 8 y instead of 16 (cheap).
__global__ void __launch_bounds__(256, 3)
k_inv_yz_pw(const float2* __restrict__ S5, const float* __restrict__ w_pw,
            const float* __restrict__ b_pw, float* __restrict__ X,
            int layer, int do_gelu) {
    int blk = blockIdx.x;
    int yg = blk & 7, x = (blk >> 3) & 63, b = blk >> 9;
    int t = threadIdx.x;
    __shared__ float2 s5s[32 * 132];   // [o][jy*8+k], padded rows  33792 B
    __shared__ float2 st[256];         // [o][k]        2 KB
    __shared__ float xt[2048];         // [c][z]        8 KB
    __shared__ float2 tw[64];
    if (t < 64) { float s, c; __sincosf(TWO_PI_OVER_64 * t, &s, &c); tw[t] = make_float2(c, s); }
    // stage s5s: coalesced float4 loads (per o: 128 contiguous float2), padded store
    #pragma unroll
    for (int i = 0; i < 8; i++) {
        int f4 = t + 256 * i;          // [0,2048): o*64 + j4
        int o = f4 >> 6, j4 = f4 & 63;
        float4 v = ((const float4*)(S5 + ((size_t)(b * 32 + o) * 64 + x) * 128))[j4];
        *(float4*)(&s5s[o * 132 + j4 * 2]) = v;
    }
    __syncthreads();
    int z = t & 63, og = t >> 6;       // og is wave-uniform (wave = 64 lanes)
    int og8 = og * 8;
    int og8u = __builtin_amdgcn_readfirstlane(og8);   // SGPR: uniform weight row base
    const float* wl = w_pw + layer * 1024 + og8u;     // uniform -> s_load
    const float* bl = b_pw + layer * 32 + og8u;       // uniform -> s_load
    float bt0 = bl[0], bt1 = bl[1], bt2 = bl[2], bt3 = bl[3];
    float bt4 = bl[4], bt5 = bl[5], bt6 = bl[6], bt7 = bl[7];
    // named z-twiddle registers (k=0 twiddle is (1,0): handled inline)
    float2 tz1 = tw[z];
    float2 tz2 = tw[(2 * z) & 63];
    float2 tz3 = tw[(3 * z) & 63];
    float2 tz4 = tw[(4 * z) & 63];
    float2 tz5 = tw[(5 * z) & 63];
    float2 tz6 = tw[(6 * z) & 63];
    float2 tz7 = tw[(7 * z) & 63];
    const float inv_n = 1.0f / 262144.0f;
    for (int yi = 0; yi < 8; yi++) {
        int y = yg * 8 + yi;
        // stage A: inverse-y for this y -> st[o][k]; padded s5s rows (conflict-free)
        {
            int o = t >> 3, k = t & 7;
            float re = 0.f, im = 0.f;
            #pragma unroll
            for (int jy = 0; jy < 16; jy++) {
                int f = jy < 8 ? jy : 48 + jy;
                float2 v = s5s[o * 132 + jy * 8 + k];
                float2 w = tw[(f * y) & 63];
                re += v.x * w.x - v.y * w.y;   // e^{+i theta}
                im += v.x * w.y + v.y * w.x;
            }
            st[t] = make_float2(re, im);
        }
        // stage B: load X column for this y
        size_t base = (size_t)b * 8388608 + (size_t)(x * 64 + y) * 64;
        #pragma unroll
        for (int i = 0; i < 8; i++) {
            int e = t + 256 * i;   // c*64 + z
            int c = e >> 6, zz = e & 63;
            xt[e] = X[base + (size_t)c * R3 + zz];
        }
        __syncthreads();
        // stage C init: inverse-z (pocketfft c2r: Re of k=0, 2x k=1..7); st reads are
        // wave-uniform b64 broadcasts (og wave-uniform). All values named scalars.
#define INVZ_S(o) (st[(o) * 8 + 0].x \
        + 2.f * (st[(o) * 8 + 1].x * tz1.x - st[(o) * 8 + 1].y * tz1.y) \
        + 2.f * (st[(o) * 8 + 2].x * tz2.x - st[(o) * 8 + 2].y * tz2.y) \
        + 2.f * (st[(o) * 8 + 3].x * tz3.x - st[(o) * 8 + 3].y * tz3.y) \
        + 2.f * (st[(o) * 8 + 4].x * tz4.x - st[(o) * 8 + 4].y * tz4.y) \
        + 2.f * (st[(o) * 8 + 5].x * tz5.x - st[(o) * 8 + 5].y * tz5.y) \
        + 2.f * (st[(o) * 8 + 6].x * tz6.x - st[(o) * 8 + 6].y * tz6.y) \
        + 2.f * (st[(o) * 8 + 7].x * tz7.x - st[(o) * 8 + 7].y * tz7.y))
        float acc0 = bt0 + INVZ_S(og8 + 0) * inv_n;
        float acc1 = bt1 + INVZ_S(og8 + 1) * inv_n;
        float acc2 = bt2 + INVZ_S(og8 + 2) * inv_n;
        float acc3 = bt3 + INVZ_S(og8 + 3) * inv_n;
        float acc4 = bt4 + INVZ_S(og8 + 4) * inv_n;
        float acc5 = bt5 + INVZ_S(og8 + 5) * inv_n;
        float acc6 = bt6 + INVZ_S(og8 + 6) * inv_n;
        float acc7 = bt7 + INVZ_S(og8 + 7) * inv_n;
#undef INVZ_S
        // stage C main: c-outer pointwise; xt once per c; weights via SMEM (s_load).
        #pragma unroll 4
        for (int c = 0; c < 32; c++) {
            float xc = xt[c * 64 + z];
            const float* wr = wl + c * 32;                 // uniform: s_load_dwordx8
            float w0 = wr[0], w1 = wr[1], w2 = wr[2], w3 = wr[3];
            float w4 = wr[4], w5 = wr[5], w6 = wr[6], w7 = wr[7];
            acc0 += xc * w0; acc1 += xc * w1; acc2 += xc * w2; acc3 += xc * w3;
            acc4 += xc * w4; acc5 += xc * w5; acc6 += xc * w6; acc7 += xc * w7;
        }
        __syncthreads();   // all st/xt reads done before next iteration overwrites
        float r;
        r = do_gelu ? geluf(acc0) : acc0; X[base + (size_t)(og8 + 0) * R3 + z] = r;
        r = do_gelu ? geluf(acc1) : acc1; X[base + (size_t)(og8 + 1) * R3 + z] = r;
        r = do_gelu ? geluf(acc2) : acc2; X[base + (size_t)(og8 + 2) * R3 + z] = r;
        r = do_gelu ? geluf(acc3) : acc3; X[base + (size_t)(og8 + 3) * R3 + z] = r;
        r = do_gelu ? geluf(acc4) : acc4; X[base + (size_t)(og8 + 4) * R3 + z] = r;
        r = do_gelu ? geluf(acc5) : acc5; X[base + (size_t)(og8 + 5) * R3 + z] = r;
        r = do_gelu ? geluf(acc6) : acc6; X[base + (size_t)(og8 + 6) * R3 + z] = r;
        r = do_gelu ? geluf(acc7) : acc7; X[base + (size_t)(og8 + 7) * R3 + z] = r;
    }
}

// ---------------- K6: head v5 — MFMA fc1 (hi/lo bf16 split) + fp32 gelu/fc2 + DPP reduce ----
// 4096 blocks, 256 threads (4 waves), 256 sites/block. Per wave-iteration: 16 sites.
typedef short bf16x8_t __attribute__((ext_vector_type(8)));
typedef float f32x4_t __attribute__((ext_vector_type(4)));

__device__ __forceinline__ float dpp_add16(float v) {
    int i;
    i = __builtin_amdgcn_update_dpp(0, __builtin_bit_cast(int, v), 0xB1, 0xF, 0xF, true);   // quad_perm xor1
    v += __builtin_bit_cast(float, i);
    i = __builtin_amdgcn_update_dpp(0, __builtin_bit_cast(int, v), 0x4E, 0xF, 0xF, true);   // quad_perm xor2
    v += __builtin_bit_cast(float, i);
    i = __builtin_amdgcn_update_dpp(0, __builtin_bit_cast(int, v), 0x141, 0xF, 0xF, true);  // row_half_mirror
    v += __builtin_bit_cast(float, i);
    i = __builtin_amdgcn_update_dpp(0, __builtin_bit_cast(int, v), 0x140, 0xF, 0xF, true);  // row_mirror
    v += __builtin_bit_cast(float, i);
    return v;
}

__global__ void __launch_bounds__(256, 2)
k_head(const float* __restrict__ X, const float* __restrict__ w1,
       const float* __restrict__ b1, const float* __restrict__ w2,
       const float* __restrict__ b2, float* __restrict__ tau_out) {
    int t = threadIdx.x;
    int lane = t & 63;
    int wv = t >> 6;                       // wave 0..3
    int m = lane & 15;                     // A-row-in-frag / D-col(h) / B-col index
    int g = lane >> 4;                     // k-group; D rows (sites) = g*4 + r
    size_t sblock = (size_t)blockIdx.x * 256;
    int b = (int)(sblock >> 18);
    size_t pblock = sblock & (R3 - 1);     // 256-aligned; R3 % 256 == 0, no b crossing
    const float* xb = X + (size_t)b * 8388608 + pblock;

    // ---- prologue (loop-invariant): B-frags hi/lo for 8 h-tiles ----
    bf16x8_t Bhi[8], Blo[8];
    #pragma unroll
    for (int tt = 0; tt < 8; tt++) {
        #pragma unroll
        for (int j = 0; j < 8; j++) {
            float w = w1[(g * 8 + j) * 128 + tt * 16 + m];
            unsigned bits = __builtin_bit_cast(unsigned, w);
            float hf = __builtin_bit_cast(float, bits & 0xFFFF0000u);
            float lof = w - hf;                                   // exact
            unsigned lb = __builtin_bit_cast(unsigned, lof);
            Bhi[tt][j] = (short)(bits >> 16);
            Blo[tt][j] = (short)(lb >> 16);
        }
    }
    // per-lane fc2 weights (h = 16*tt + m), fc1 bias, fc2 bias
    float w2r[8][6];
    #pragma unroll
    for (int tt = 0; tt < 8; tt++)
        #pragma unroll
        for (int o = 0; o < 6; o++) w2r[tt][o] = w2[(tt * 16 + m) * 6 + o];
    float b1r[8];
    #pragma unroll
    for (int tt = 0; tt < 8; tt++) b1r[tt] = b1[tt * 16 + m];
    float b2m = b2[m < 6 ? m : 0];

    for (int it = 0; it < 4; it++) {
        int s16 = wv * 64 + it * 16;       // site base (within block) for this 16-site tile
        // ---- A-frags: lane holds X[c = g*8+j][site = s16 + m], hi/lo split ----
        bf16x8_t Ahi, Alo;
        #pragma unroll
        for (int j = 0; j < 8; j++) {
            float xv = xb[(size_t)(g * 8 + j) * R3 + s16 + m];
            unsigned bits = __builtin_bit_cast(unsigned, xv);
            float hf = __builtin_bit_cast(float, bits & 0xFFFF0000u);
            float lof = xv - hf;                                  // exact
            unsigned lb = __builtin_bit_cast(unsigned, lof);
            Ahi[j] = (short)(bits >> 16);
            Alo[j] = (short)(lb >> 16);
        }
        // ---- fc1 (one MFMA contracts full K=32) + gelu + fc2 partials ----
        float p0[6] = {0.f, 0.f, 0.f, 0.f, 0.f, 0.f};
        float p1[6] = {0.f, 0.f, 0.f, 0.f, 0.f, 0.f};
        float p2[6] = {0.f, 0.f, 0.f, 0.f, 0.f, 0.f};
        float p3[6] = {0.f, 0.f, 0.f, 0.f, 0.f, 0.f};
        #pragma unroll
        for (int tt = 0; tt < 8; tt++) {
            f32x4_t d = {0.f, 0.f, 0.f, 0.f};
            d = __builtin_amdgcn_mfma_f32_16x16x32_bf16(Ahi, Bhi[tt], d, 0, 0, 0);
            d = __builtin_amdgcn_mfma_f32_16x16x32_bf16(Ahi, Blo[tt], d, 0, 0, 0);
            d = __builtin_amdgcn_mfma_f32_16x16x32_bf16(Alo, Bhi[tt], d, 0, 0, 0);
            // d[r] = fc1[site = s16 + g*4 + r][h = 16*tt + m]
            float a0 = geluf(d[0] + b1r[tt]);
            float a1 = geluf(d[1] + b1r[tt]);
            float a2 = geluf(d[2] + b1r[tt]);
            float a3 = geluf(d[3] + b1r[tt]);
            #pragma unroll
            for (int o = 0; o < 6; o++) {
                float w = w2r[tt][o];
                p0[o] += a0 * w; p1[o] += a1 * w; p2[o] += a2 * w; p3[o] += a3 * w;
            }
        }
        // ---- reduce over the 16 m-lanes (VALU DPP butterfly), select o = m, store ----
        float q0 = 0.f, q1 = 0.f, q2 = 0.f, q3 = 0.f;
        #pragma unroll
        for (int o = 0; o < 6; o++) {
            float r0 = dpp_add16(p0[o]);
            float r1 = dpp_add16(p1[o]);
            float r2 = dpp_add16(p2[o]);
            float r3 = dpp_add16(p3[o]);
            q0 = (m == o) ? r0 : q0;
            q1 = (m == o) ? r1 : q1;
            q2 = (m == o) ? r2 : q2;
            q3 = (m == o) ? r3 : q3;
        }
        if (m < 6) {
            float4 vv = make_float4(q0 + b2m, q1 + b2m, q2 + b2m, q3 + b2m);
            *(float4*)(tau_out + (size_t)b * 6 * R3 + (size_t)m * R3 + pblock + s16 + g * 4) = vv;
        }
    }
}

// ---------------- K7: NS hard core + combine ----------------
// 12288 blocks, 256 threads; s over B*3*R3
__global__ void k_hard(const float* __restrict__ u, const float* __restrict__ tau,
                       float* __restrict__ out0) {
    size_t s = (size_t)blockIdx.x * 256 + threadIdx.x;
    int bi = (int)(s >> 18);
    int b = bi / 3, i = bi % 3;
    size_t p = s & (R3 - 1);
    int x = (int)(p >> 12), y = ((int)p >> 6) & 63, z = (int)p & 63;
    const float dx = TWO_PI_OVER_64;
    const float inv2dx = 1.0f / (2.0f * dx);
    const float invdx2 = 1.0f / (dx * dx);
    const float* ub = u + (size_t)b * 3 * R3;
    const float* ui = ub + (size_t)i * R3;
    int xp = (x + 1) & 63, xm = (x + 63) & 63;
    int yp = (y + 1) & 63, ym = (y + 63) & 63;
    int zp = (z + 1) & 63, zm = (z + 63) & 63;
    float c0 = ui[p];
    float upx = ui[((size_t)xp << 12) | (y << 6) | z], umx = ui[((size_t)xm << 12) | (y << 6) | z];
    float upy = ui[((size_t)x << 12) | (yp << 6) | z], umy = ui[((size_t)x << 12) | (ym << 6) | z];
    float upz = ui[((size_t)x << 12) | (y << 6) | zp], umz = ui[((size_t)x << 12) | (y << 6) | zm];
    float u0c = ub[p], u1c = ub[R3 + p], u2c = ub[2 * R3 + p];
    float conv = -(u0c * (upx - umx) + u1c * (upy - umy) + u2c * (upz - umz)) * inv2dx;
    float diff = (upx + umx + upy + umy + upz + umz - 6.0f * c0) * invdx2;
    float tauv = tau[(size_t)b * 6 * R3 + (size_t)i * R3 + p];
    out0[s] = conv + 0.000185f * diff + 0.001f * tauv;
}

extern "C" void kernel_launch(void* const* d_in, const int* in_sizes, int n_in,
                              void* d_out, int out_size, void* d_ws, size_t ws_size,
                              hipStream_t stream) {
    const float* u      = (const float*)d_in[0];
    const float* fc0_w  = (const float*)d_in[1];
    const float* fc0_b  = (const float*)d_in[2];
    const float* spec_w = (const float*)d_in[3];
    const float* w_pw   = (const float*)d_in[4];
    const float* b_pw   = (const float*)d_in[5];
    const float* fc1_w  = (const float*)d_in[6];
    const float* fc1_b  = (const float*)d_in[7];
    const float* fc2_w  = (const float*)d_in[8];
    const float* fc2_b  = (const float*)d_in[9];
    float* out = (float*)d_out;

    // d_ws: only the activation tensor X (B*32*64^3 floats = 128 MiB), updated in place.
    float* X = (float*)d_ws;

    // Spectral stage buffers live in d_out's dead space (20 MiB of 36 MiB total).
    // All are dead before k_head/k_hard overwrite tau/du at the end.
    float2* S2 = (float2*)(out);                // 1048576 float2 =  8 MiB, floats [0, 2097152)
    float2* S3 = (float2*)(out + 2097152);      //  262144 float2 =  2 MiB
    float2* S4 = (float2*)(out + 2621440);      //  262144 float2 =  2 MiB
    float2* S5 = (float2*)(out + 3145728);      // 1048576 float2 =  8 MiB, ends at float 5242880

    k_fc0<<<4096, 256, 0, stream>>>(u, fc0_w, fc0_b, X);

    for (int l = 0; l < 4; l++) {
        k_fwd_zy<<<2048, 256, 0, stream>>>(X, S2);
        k_fwd_x<<<1024, 256, 0, stream>>>(S2, S3);
        k_specmul<<<1024, 128, 0, stream>>>(S3, spec_w, S4, l);
        k_inv_x<<<1024, 256, 0, stream>>>(S4, S5);
        k_inv_yz_pw<<<2048, 256, 0, stream>>>(S5, w_pw, b_pw, X, l, (l < 3) ? 1 : 0);
    }

    float* tau_out = out + (size_t)4 * 3 * R3;   // second output section (offset 3145728)
    k_head<<<4096, 256, 0, stream>>>(X, fc1_w, fc1_b, fc2_w, fc2_b, tau_out);
    k_hard<<<12288, 256, 0, stream>>>(u, tau_out, out);
}

// Round 10
// 1056.909 us; speedup vs baseline: 1.4134x; 1.0196x over previous
//
#include <hip/hip_runtime.h>
#include <hip/hip_bf16.h>

#define RES 64
#define WIDTH 32
#define MODES 8
#define R3 262144            // 64^3
#define TWO_PI_OVER_64 0.09817477042468103f

__device__ __forceinline__ float geluf(float x) {
    // jax.nn.gelu approximate=True: x * sigmoid(1.595769...*(x+0.044715x^3))
    float g = 1.5957691216057308f * (x + 0.044715f * x * x * x);
    return x * __builtin_amdgcn_rcpf(1.0f + __expf(-g));
}

// Compile-time twiddle table: constexpr Taylor cos/sin so the fully-unrolled z-DFT
// folds every twiddle to a literal (v_fmac with inline constant, ZERO LDS reads).
constexpr double tcos_(double x) {
    double r = 1.0, term = 1.0;
    for (int i = 1; i <= 12; i++) { term *= -x * x / ((2.0 * i - 1.0) * (2.0 * i)); r += term; }
    return r;
}
constexpr double tsin_(double x) {
    double r = x, term = x;
    for (int i = 1; i <= 12; i++) { term *= -x * x / ((2.0 * i) * (2.0 * i + 1.0)); r += term; }
    return r;
}
struct Tw64 { float c[64]; float s[64]; };
constexpr Tw64 mkTw() {
    Tw64 t{};
    const double th = 6.283185307179586476925286766559 / 64.0;
    for (int i = 0; i < 64; i++) {
        double a = th * (i <= 32 ? i : i - 64);   // reduce to [-pi, pi] for Taylor
        t.c[i] = (float)tcos_(a);
        t.s[i] = (float)tsin_(a);
    }
    return t;
}
constexpr Tw64 TWT = mkTw();

// ---------------- K0: fc0 pointwise (3 -> 32) ----------------
__global__ void k_fc0(const float* __restrict__ u, const float* __restrict__ w,
                      const float* __restrict__ bias, float* __restrict__ X) {
    __shared__ float ws[96];
    __shared__ float bs[32];
    int t = threadIdx.x;
    if (t < 96) ws[t] = w[t];
    if (t < 32) bs[t] = bias[t];
    __syncthreads();
    size_t s = (size_t)blockIdx.x * 256 + t;     // over B*R3 = 1048576
    int b = (int)(s >> 18);
    size_t p = s & (R3 - 1);
    const float* ub = u + (size_t)b * 3 * R3;
    float u0 = ub[p], u1 = ub[R3 + p], u2 = ub[2 * R3 + p];
    float* xb = X + (size_t)b * 32 * R3;
    #pragma unroll
    for (int o = 0; o < 32; o++) {
        xb[(size_t)o * R3 + p] = bs[o] + u0 * ws[o] + u1 * ws[32 + o] + u2 * ws[64 + o];
    }
}

// ---------------- K1: fused forward DFT over z (64->8) and y (64->16 bins), v2 ----------------
// v2: one row per LANE, direct global b128 reads (no LDS staging, no bank conflicts),
// literal twiddles (constexpr TWT) + z->z+32 even/odd fold: 576 FMA/row, zero LDS in z-loop.
// Block = 4 (b,c,x) planes (one per wave). 2048 blocks, 256 threads.
__global__ void __launch_bounds__(256, 6)
k_fwd_zy(const float* __restrict__ X, float2* __restrict__ S2) {
    int t = threadIdx.x;
    int q = t >> 6, y = t & 63;                  // wave q handles plane bcx0+q, lane = y row
    int bcx0 = blockIdx.x * 4;
    __shared__ float2 zt[4][8][66];              // [plane][kz][y], padded 64->66 (conflict-free)
    __shared__ float2 tw[64];
    if (t < 64) { float s, c; __sincosf(TWO_PI_OVER_64 * t, &s, &c); tw[t] = make_float2(c, s); }

    // ---- stage 1: z-DFT (64 -> 8 bins), one row per thread ----
    const float* row = X + (size_t)(bcx0 + q) * 4096 + (size_t)y * 64;
    float re[8], im[8];
    #pragma unroll
    for (int k = 0; k < 8; k++) { re[k] = 0.f; im[k] = 0.f; }
    #pragma unroll
    for (int zb = 0; zb < 8; zb++) {
        float xa[4], xb4[4];
        *(float4*)xa  = *(const float4*)(row + zb * 4);
        *(float4*)xb4 = *(const float4*)(row + zb * 4 + 32);
        #pragma unroll
        for (int j = 0; j < 4; j++) {
            int z = zb * 4 + j;                  // z in [0,32)
            float sv = xa[j] + xb4[j];           // even-k fold: x[z] + x[z+32]
            float dv = xa[j] - xb4[j];           // odd-k fold:  x[z] - x[z+32]
            #pragma unroll
            for (int k = 0; k < 8; k++) {
                float v = (k & 1) ? dv : sv;
                re[k] += v * TWT.c[(k * z) & 63];   // literal constants after unroll
                im[k] -= v * TWT.s[(k * z) & 63];
            }
        }
    }
    #pragma unroll
    for (int k = 0; k < 8; k++) zt[q][k][y] = make_float2(re[k], im[k]);
    __syncthreads();

    // ---- stage 2: y-DFT (64 -> 16 bins), 2 outputs per thread ----
    int l = t & 63;
    int jy = l >> 2, kp = l & 3;
    int f = jy < 8 ? jy : 48 + jy;
    int k0 = kp * 2;
    float re0 = 0.f, im0 = 0.f, re1 = 0.f, im1 = 0.f;
    #pragma unroll 8
    for (int yy = 0; yy < 64; yy++) {
        float2 w = tw[(f * yy) & 63];
        float2 v0 = zt[q][k0][yy];
        float2 v1 = zt[q][k0 + 1][yy];
        re0 += v0.x * w.x + v0.y * w.y;          // * conj(w)
        im0 += v0.y * w.x - v0.x * w.y;
        re1 += v1.x * w.x + v1.y * w.y;
        im1 += v1.y * w.x - v1.x * w.y;
    }
    float2* dst = S2 + (size_t)(bcx0 + q) * 128 + jy * 8 + k0;
    dst[0] = make_float2(re0, im0);
    dst[1] = make_float2(re1, im1);
}

// ---------------- K2: forward DFT over x: 64 -> 16 bins ----------------
// block per (bc, kz); 1024 blocks, 256 threads (jx16 x jy16)
__global__ void k_fwd_x(const float2* __restrict__ S2, float2* __restrict__ S3) {
    int bc = blockIdx.x >> 3, kz = blockIdx.x & 7;
    int t = threadIdx.x;
    __shared__ float2 in[64 * 16];  // [x][jy]
    __shared__ float2 tw[64];
    if (t < 64) { float s, c; __sincosf(TWO_PI_OVER_64 * t, &s, &c); tw[t] = make_float2(c, s); }
    #pragma unroll
    for (int i = 0; i < 4; i++) {
        int e = t + 256 * i;        // e = x*16 + jy
        in[e] = S2[((size_t)bc * 1024 + e) * 8 + kz];
    }
    __syncthreads();
    int jx = t >> 4, jy = t & 15;
    int f = jx < 8 ? jx : 48 + jx;
    float re = 0.f, im = 0.f;
    for (int x = 0; x < 64; x++) {
        float2 v = in[x * 16 + jy];
        float2 w = tw[(f * x) & 63];
        re += v.x * w.x + v.y * w.y;
        im += v.y * w.x - v.x * w.y;
    }
    // S3 layout: [b][i][mode], mode = (jx*16+jy)*8 + kz
    S3[(size_t)bc * 2048 + (size_t)t * 8 + kz] = make_float2(re, im);
}

// ---------------- K3: spectral multiply, two m3-modes per block ----------------
// out[b,o,mode] = sum_i in[b,i,mode]*W[i,o]; 1024 blocks, 128 threads (b4 x o32)
__global__ void k_specmul(const float2* __restrict__ S3, const float* __restrict__ spec_w,
                          float2* __restrict__ S4, int layer) {
    int mp = blockIdx.x;                 // mode pair
    int t = threadIdx.x;
    int jxy = mp >> 2;                   // jx*16+jy
    int kz0 = (mp & 3) * 2;
    int jy = jxy & 15, jx = jxy >> 4;
    int corner = (jx >= 8 ? 1 : 0) + (jy >= 8 ? 2 : 0);
    int m1 = jx & 7, m2 = jy & 7;
    int mode0 = jxy * 8 + kz0;
    __shared__ float4 W4[1024];          // [i][o] -> (re0,im0,re1,im1)
    __shared__ float2 inb[2][128];       // [mode][b*32+i]
    const float* wbase = spec_w + (size_t)layer * 4194304 + (size_t)corner * 1048576
                       + m1 * 128 + m2 * 16 + kz0 * 2;
    #pragma unroll
    for (int j = 0; j < 8; j++) {
        int e = t + 128 * j;    // i*32 + o
        int i = e >> 5, o = e & 31;
        W4[e] = *(const float4*)(wbase + (size_t)i * 32768 + (size_t)o * 1024);
    }
    inb[0][t] = S3[(size_t)t * 2048 + mode0];
    inb[1][t] = S3[(size_t)t * 2048 + mode0 + 1];
    __syncthreads();
    int b = t >> 5, o = t & 31;
    float re0 = 0.f, im0 = 0.f, re1 = 0.f, im1 = 0.f;
    #pragma unroll 8
    for (int i = 0; i < 32; i++) {
        float2 a0 = inb[0][b * 32 + i];
        float2 a1 = inb[1][b * 32 + i];
        float4 w = W4[i * 32 + o];
        re0 += a0.x * w.x - a0.y * w.y;
        im0 += a0.x * w.y + a0.y * w.x;
        re1 += a1.x * w.z - a1.y * w.w;
        im1 += a1.x * w.w + a1.y * w.z;
    }
    S4[(size_t)(b * 32 + o) * 2048 + mode0]     = make_float2(re0, im0);
    S4[(size_t)(b * 32 + o) * 2048 + mode0 + 1] = make_float2(re1, im1);
}

// ---------------- K4: inverse DFT over x: 16 bins -> 64 ----------------
// block per (bo, kz); 1024 blocks, 256 threads
__global__ void k_inv_x(const float2* __restrict__ S4, float2* __restrict__ S5) {
    int bo = blockIdx.x >> 3, kz = blockIdx.x & 7;
    int t = threadIdx.x;
    __shared__ float2 in[256];   // [jx][jy]
    __shared__ float2 tw[64];
    if (t < 64) { float s, c; __sincosf(TWO_PI_OVER_64 * t, &s, &c); tw[t] = make_float2(c, s); }
    in[t] = S4[(size_t)bo * 2048 + (size_t)t * 8 + kz];
    __syncthreads();
    int x = t & 63, g = t >> 6;
    #pragma unroll
    for (int m = 0; m < 4; m++) {
        int jy = g + 4 * m;
        float re = 0.f, im = 0.f;
        #pragma unroll
        for (int jx = 0; jx < 16; jx++) {
            int f = jx < 8 ? jx : 48 + jx;
            float2 v = in[jx * 16 + jy];
            float2 w = tw[(f * x) & 63];
            re += v.x * w.x - v.y * w.y;   // e^{+i theta}
            im += v.x * w.y + v.y * w.x;
        }
        // S5 layout [bo][x][jy][kz]
        S5[((size_t)bo * 64 + x) * 128 + jy * 8 + kz] = make_float2(re, im);
    }
}

// ---------------- K5: fused inverse-y + inverse-z DFT + pointwise + add + gelu (IN-PLACE on X) ----
// v8 = v7 (verified 115 us/dispatch: s5s in LDS, 2048 blocks, 8 y/block) + T14 prefetch:
// yi+1's X column is loaded into xr[8] registers right after the mid-barrier so its ~300-500
// cycle (L3-resident X) latency hides under stage C's ~600-cycle compute, instead of gating
// the next iteration's mid-barrier. Only +8 VGPRs on top of 68; the 44.5 KB LDS already caps
// occupancy at 3 blocks/CU (3 waves/SIMD, VGPR budget ~170) so the v4/v6 spill incentive is
// structurally absent. Spill tripwire: FETCH_SIZE must stay ~98 MB (>200 MB = spill, revert).
// Arithmetic values/order bit-identical to v7.
__global__ void __launch_bounds__(256, 3)
k_inv_yz_pw(const float2* __restrict__ S5, const float* __restrict__ w_pw,
            const float* __restrict__ b_pw, float* __restrict__ X,
            int layer, int do_gelu) {
    int blk = blockIdx.x;
    int yg = blk & 7, x = (blk >> 3) & 63, b = blk >> 9;
    int t = threadIdx.x;
    __shared__ float2 s5s[32 * 132];   // [o][jy*8+k], padded rows  33792 B
    __shared__ float2 st[256];         // [o][k]        2 KB
    __shared__ float xt[2048];         // [c][z]        8 KB
    __shared__ float2 tw[64];
    if (t < 64) { float s, c; __sincosf(TWO_PI_OVER_64 * t, &s, &c); tw[t] = make_float2(c, s); }
    // stage s5s: coalesced float4 loads (per o: 128 contiguous float2), padded store
    #pragma unroll
    for (int i = 0; i < 8; i++) {
        int f4 = t + 256 * i;          // [0,2048): o*64 + j4
        int o = f4 >> 6, j4 = f4 & 63;
        float4 v = ((const float4*)(S5 + ((size_t)(b * 32 + o) * 64 + x) * 128))[j4];
        *(float4*)(&s5s[o * 132 + j4 * 2]) = v;
    }
    size_t base0 = (size_t)b * 8388608 + (size_t)(x * 64 + yg * 8) * 64;
    // prologue: prefetch X column for yi = 0 into registers (overlaps s5s staging)
    float xr0, xr1, xr2, xr3, xr4, xr5, xr6, xr7;
    {
        const float* xp = X + base0 + (t & 63);
        int c0 = t >> 6;               // c = c0 + 4*i for i-th load
        xr0 = xp[(size_t)(c0 +  0) * R3];
        xr1 = xp[(size_t)(c0 +  4) * R3];
        xr2 = xp[(size_t)(c0 +  8) * R3];
        xr3 = xp[(size_t)(c0 + 12) * R3];
        xr4 = xp[(size_t)(c0 + 16) * R3];
        xr5 = xp[(size_t)(c0 + 20) * R3];
        xr6 = xp[(size_t)(c0 + 24) * R3];
        xr7 = xp[(size_t)(c0 + 28) * R3];
    }
    __syncthreads();
    int z = t & 63, og = t >> 6;       // og is wave-uniform (wave = 64 lanes)
    int og8 = og * 8;
    int og8u = __builtin_amdgcn_readfirstlane(og8);   // SGPR: uniform weight row base
    const float* wl = w_pw + layer * 1024 + og8u;     // uniform -> s_load
    const float* bl = b_pw + layer * 32 + og8u;       // uniform -> s_load
    float bt0 = bl[0], bt1 = bl[1], bt2 = bl[2], bt3 = bl[3];
    float bt4 = bl[4], bt5 = bl[5], bt6 = bl[6], bt7 = bl[7];
    // named z-twiddle registers (k=0 twiddle is (1,0): handled inline)
    float2 tz1 = tw[z];
    float2 tz2 = tw[(2 * z) & 63];
    float2 tz3 = tw[(3 * z) & 63];
    float2 tz4 = tw[(4 * z) & 63];
    float2 tz5 = tw[(5 * z) & 63];
    float2 tz6 = tw[(6 * z) & 63];
    float2 tz7 = tw[(7 * z) & 63];
    const float inv_n = 1.0f / 262144.0f;
    for (int yi = 0; yi < 8; yi++) {
        int y = yg * 8 + yi;
        size_t base = base0 + (size_t)yi * 64;
        // stage B: commit prefetched registers to xt (xt[c*64 + z], c = (t>>6) + 4*i)
        {
            int e = t;                  // e = c*64' layout: e + 256*i == (c0+4i)*64 + z
            xt[e +    0] = xr0; xt[e +  256] = xr1; xt[e +  512] = xr2; xt[e +  768] = xr3;
            xt[e + 1024] = xr4; xt[e + 1280] = xr5; xt[e + 1536] = xr6; xt[e + 1792] = xr7;
        }
        // stage A: inverse-y for this y -> st[o][k]; padded s5s rows (conflict-free)
        {
            int o = t >> 3, k = t & 7;
            float re = 0.f, im = 0.f;
            #pragma unroll
            for (int jy = 0; jy < 16; jy++) {
                int f = jy < 8 ? jy : 48 + jy;
                float2 v = s5s[o * 132 + jy * 8 + k];
                float2 w = tw[(f * y) & 63];
                re += v.x * w.x - v.y * w.y;   // e^{+i theta}
                im += v.x * w.y + v.y * w.x;
            }
            st[t] = make_float2(re, im);
        }
        __syncthreads();
        // T14 prefetch: issue yi+1's X loads now; latency hides under stage C
        if (yi < 7) {
            const float* xp = X + base + 64 + (t & 63);
            int c0 = t >> 6;
            xr0 = xp[(size_t)(c0 +  0) * R3];
            xr1 = xp[(size_t)(c0 +  4) * R3];
            xr2 = xp[(size_t)(c0 +  8) * R3];
            xr3 = xp[(size_t)(c0 + 12) * R3];
            xr4 = xp[(size_t)(c0 + 16) * R3];
            xr5 = xp[(size_t)(c0 + 20) * R3];
            xr6 = xp[(size_t)(c0 + 24) * R3];
            xr7 = xp[(size_t)(c0 + 28) * R3];
        }
        // stage C init: inverse-z (pocketfft c2r: Re of k=0, 2x k=1..7); st reads are
        // wave-uniform b64 broadcasts (og wave-uniform). All values named scalars.
#define INVZ_S(o) (st[(o) * 8 + 0].x \
        + 2.f * (st[(o) * 8 + 1].x * tz1.x - st[(o) * 8 + 1].y * tz1.y) \
        + 2.f * (st[(o) * 8 + 2].x * tz2.x - st[(o) * 8 + 2].y * tz2.y) \
        + 2.f * (st[(o) * 8 + 3].x * tz3.x - st[(o) * 8 + 3].y * tz3.y) \
        + 2.f * (st[(o) * 8 + 4].x * tz4.x - st[(o) * 8 + 4].y * tz4.y) \
        + 2.f * (st[(o) * 8 + 5].x * tz5.x - st[(o) * 8 + 5].y * tz5.y) \
        + 2.f * (st[(o) * 8 + 6].x * tz6.x - st[(o) * 8 + 6].y * tz6.y) \
        + 2.f * (st[(o) * 8 + 7].x * tz7.x - st[(o) * 8 + 7].y * tz7.y))
        float acc0 = bt0 + INVZ_S(og8 + 0) * inv_n;
        float acc1 = bt1 + INVZ_S(og8 + 1) * inv_n;
        float acc2 = bt2 + INVZ_S(og8 + 2) * inv_n;
        float acc3 = bt3 + INVZ_S(og8 + 3) * inv_n;
        float acc4 = bt4 + INVZ_S(og8 + 4) * inv_n;
        float acc5 = bt5 + INVZ_S(og8 + 5) * inv_n;
        float acc6 = bt6 + INVZ_S(og8 + 6) * inv_n;
        float acc7 = bt7 + INVZ_S(og8 + 7) * inv_n;
#undef INVZ_S
        // stage C main: c-outer pointwise; xt once per c; weights via SMEM (s_load).
        #pragma unroll 4
        for (int c = 0; c < 32; c++) {
            float xc = xt[c * 64 + z];
            const float* wr = wl + c * 32;                 // uniform: s_load_dwordx8
            float w0 = wr[0], w1 = wr[1], w2 = wr[2], w3 = wr[3];
            float w4 = wr[4], w5 = wr[5], w6 = wr[6], w7 = wr[7];
            acc0 += xc * w0; acc1 += xc * w1; acc2 += xc * w2; acc3 += xc * w3;
            acc4 += xc * w4; acc5 += xc * w5; acc6 += xc * w6; acc7 += xc * w7;
        }
        __syncthreads();   // all st/xt reads done before next iteration overwrites
        float r;
        r = do_gelu ? geluf(acc0) : acc0; X[base + (size_t)(og8 + 0) * R3 + z] = r;
        r = do_gelu ? geluf(acc1) : acc1; X[base + (size_t)(og8 + 1) * R3 + z] = r;
        r = do_gelu ? geluf(acc2) : acc2; X[base + (size_t)(og8 + 2) * R3 + z] = r;
        r = do_gelu ? geluf(acc3) : acc3; X[base + (size_t)(og8 + 3) * R3 + z] = r;
        r = do_gelu ? geluf(acc4) : acc4; X[base + (size_t)(og8 + 4) * R3 + z] = r;
        r = do_gelu ? geluf(acc5) : acc5; X[base + (size_t)(og8 + 5) * R3 + z] = r;
        r = do_gelu ? geluf(acc6) : acc6; X[base + (size_t)(og8 + 6) * R3 + z] = r;
        r = do_gelu ? geluf(acc7) : acc7; X[base + (size_t)(og8 + 7) * R3 + z] = r;
    }
}

// ---------------- K6: head v5 — MFMA fc1 (hi/lo bf16 split) + fp32 gelu/fc2 + DPP reduce ----
// 4096 blocks, 256 threads (4 waves), 256 sites/block. Per wave-iteration: 16 sites.
typedef short bf16x8_t __attribute__((ext_vector_type(8)));
typedef float f32x4_t __attribute__((ext_vector_type(4)));

__device__ __forceinline__ float dpp_add16(float v) {
    int i;
    i = __builtin_amdgcn_update_dpp(0, __builtin_bit_cast(int, v), 0xB1, 0xF, 0xF, true);   // quad_perm xor1
    v += __builtin_bit_cast(float, i);
    i = __builtin_amdgcn_update_dpp(0, __builtin_bit_cast(int, v), 0x4E, 0xF, 0xF, true);   // quad_perm xor2
    v += __builtin_bit_cast(float, i);
    i = __builtin_amdgcn_update_dpp(0, __builtin_bit_cast(int, v), 0x141, 0xF, 0xF, true);  // row_half_mirror
    v += __builtin_bit_cast(float, i);
    i = __builtin_amdgcn_update_dpp(0, __builtin_bit_cast(int, v), 0x140, 0xF, 0xF, true);  // row_mirror
    v += __builtin_bit_cast(float, i);
    return v;
}

__global__ void __launch_bounds__(256, 2)
k_head(const float* __restrict__ X, const float* __restrict__ w1,
       const float* __restrict__ b1, const float* __restrict__ w2,
       const float* __restrict__ b2, float* __restrict__ tau_out) {
    int t = threadIdx.x;
    int lane = t & 63;
    int wv = t >> 6;                       // wave 0..3
    int m = lane & 15;                     // A-row-in-frag / D-col(h) / B-col index
    int g = lane >> 4;                     // k-group; D rows (sites) = g*4 + r
    size_t sblock = (size_t)blockIdx.x * 256;
    int b = (int)(sblock >> 18);
    size_t pblock = sblock & (R3 - 1);     // 256-aligned; R3 % 256 == 0, no b crossing
    const float* xb = X + (size_t)b * 8388608 + pblock;

    // ---- prologue (loop-invariant): B-frags hi/lo for 8 h-tiles ----
    bf16x8_t Bhi[8], Blo[8];
    #pragma unroll
    for (int tt = 0; tt < 8; tt++) {
        #pragma unroll
        for (int j = 0; j < 8; j++) {
            float w = w1[(g * 8 + j) * 128 + tt * 16 + m];
            unsigned bits = __builtin_bit_cast(unsigned, w);
            float hf = __builtin_bit_cast(float, bits & 0xFFFF0000u);
            float lof = w - hf;                                   // exact
            unsigned lb = __builtin_bit_cast(unsigned, lof);
            Bhi[tt][j] = (short)(bits >> 16);
            Blo[tt][j] = (short)(lb >> 16);
        }
    }
    // per-lane fc2 weights (h = 16*tt + m), fc1 bias, fc2 bias
    float w2r[8][6];
    #pragma unroll
    for (int tt = 0; tt < 8; tt++)
        #pragma unroll
        for (int o = 0; o < 6; o++) w2r[tt][o] = w2[(tt * 16 + m) * 6 + o];
    float b1r[8];
    #pragma unroll
    for (int tt = 0; tt < 8; tt++) b1r[tt] = b1[tt * 16 + m];
    float b2m = b2[m < 6 ? m : 0];

    for (int it = 0; it < 4; it++) {
        int s16 = wv * 64 + it * 16;       // site base (within block) for this 16-site tile
        // ---- A-frags: lane holds X[c = g*8+j][site = s16 + m], hi/lo split ----
        bf16x8_t Ahi, Alo;
        #pragma unroll
        for (int j = 0; j < 8; j++) {
            float xv = xb[(size_t)(g * 8 + j) * R3 + s16 + m];
            unsigned bits = __builtin_bit_cast(unsigned, xv);
            float hf = __builtin_bit_cast(float, bits & 0xFFFF0000u);
            float lof = xv - hf;                                  // exact
            unsigned lb = __builtin_bit_cast(unsigned, lof);
            Ahi[j] = (short)(bits >> 16);
            Alo[j] = (short)(lb >> 16);
        }
        // ---- fc1 (one MFMA contracts full K=32) + gelu + fc2 partials ----
        float p0[6] = {0.f, 0.f, 0.f, 0.f, 0.f, 0.f};
        float p1[6] = {0.f, 0.f, 0.f, 0.f, 0.f, 0.f};
        float p2[6] = {0.f, 0.f, 0.f, 0.f, 0.f, 0.f};
        float p3[6] = {0.f, 0.f, 0.f, 0.f, 0.f, 0.f};
        #pragma unroll
        for (int tt = 0; tt < 8; tt++) {
            f32x4_t d = {0.f, 0.f, 0.f, 0.f};
            d = __builtin_amdgcn_mfma_f32_16x16x32_bf16(Ahi, Bhi[tt], d, 0, 0, 0);
            d = __builtin_amdgcn_mfma_f32_16x16x32_bf16(Ahi, Blo[tt], d, 0, 0, 0);
            d = __builtin_amdgcn_mfma_f32_16x16x32_bf16(Alo, Bhi[tt], d, 0, 0, 0);
            // d[r] = fc1[site = s16 + g*4 + r][h = 16*tt + m]
            float a0 = geluf(d[0] + b1r[tt]);
            float a1 = geluf(d[1] + b1r[tt]);
            float a2 = geluf(d[2] + b1r[tt]);
            float a3 = geluf(d[3] + b1r[tt]);
            #pragma unroll
            for (int o = 0; o < 6; o++) {
                float w = w2r[tt][o];
                p0[o] += a0 * w; p1[o] += a1 * w; p2[o] += a2 * w; p3[o] += a3 * w;
            }
        }
        // ---- reduce over the 16 m-lanes (VALU DPP butterfly), select o = m, store ----
        float q0 = 0.f, q1 = 0.f, q2 = 0.f, q3 = 0.f;
        #pragma unroll
        for (int o = 0; o < 6; o++) {
            float r0 = dpp_add16(p0[o]);
            float r1 = dpp_add16(p1[o]);
            float r2 = dpp_add16(p2[o]);
            float r3 = dpp_add16(p3[o]);
            q0 = (m == o) ? r0 : q0;
            q1 = (m == o) ? r1 : q1;
            q2 = (m == o) ? r2 : q2;
            q3 = (m == o) ? r3 : q3;
        }
        if (m < 6) {
            float4 vv = make_float4(q0 + b2m, q1 + b2m, q2 + b2m, q3 + b2m);
            *(float4*)(tau_out + (size_t)b * 6 * R3 + (size_t)m * R3 + pblock + s16 + g * 4) = vv;
        }
    }
}

// ---------------- K7: NS hard core + combine ----------------
// 12288 blocks, 256 threads; s over B*3*R3
__global__ void k_hard(const float* __restrict__ u, const float* __restrict__ tau,
                       float* __restrict__ out0) {
    size_t s = (size_t)blockIdx.x * 256 + threadIdx.x;
    int bi = (int)(s >> 18);
    int b = bi / 3, i = bi % 3;
    size_t p = s & (R3 - 1);
    int x = (int)(p >> 12), y = ((int)p >> 6) & 63, z = (int)p & 63;
    const float dx = TWO_PI_OVER_64;
    const float inv2dx = 1.0f / (2.0f * dx);
    const float invdx2 = 1.0f / (dx * dx);
    const float* ub = u + (size_t)b * 3 * R3;
    const float* ui = ub + (size_t)i * R3;
    int xp = (x + 1) & 63, xm = (x + 63) & 63;
    int yp = (y + 1) & 63, ym = (y + 63) & 63;
    int zp = (z + 1) & 63, zm = (z + 63) & 63;
    float c0 = ui[p];
    float upx = ui[((size_t)xp << 12) | (y << 6) | z], umx = ui[((size_t)xm << 12) | (y << 6) | z];
    float upy = ui[((size_t)x << 12) | (yp << 6) | z], umy = ui[((size_t)x << 12) | (ym << 6) | z];
    float upz = ui[((size_t)x << 12) | (y << 6) | zp], umz = ui[((size_t)x << 12) | (y << 6) | zm];
    float u0c = ub[p], u1c = ub[R3 + p], u2c = ub[2 * R3 + p];
    float conv = -(u0c * (upx - umx) + u1c * (upy - umy) + u2c * (upz - umz)) * inv2dx;
    float diff = (upx + umx + upy + umy + upz + umz - 6.0f * c0) * invdx2;
    float tauv = tau[(size_t)b * 6 * R3 + (size_t)i * R3 + p];
    out0[s] = conv + 0.000185f * diff + 0.001f * tauv;
}

extern "C" void kernel_launch(void* const* d_in, const int* in_sizes, int n_in,
                              void* d_out, int out_size, void* d_ws, size_t ws_size,
                              hipStream_t stream) {
    const float* u      = (const float*)d_in[0];
    const float* fc0_w  = (const float*)d_in[1];
    const float* fc0_b  = (const float*)d_in[2];
    const float* spec_w = (const float*)d_in[3];
    const float* w_pw   = (const float*)d_in[4];
    const float* b_pw   = (const float*)d_in[5];
    const float* fc1_w  = (const float*)d_in[6];
    const float* fc1_b  = (const float*)d_in[7];
    const float* fc2_w  = (const float*)d_in[8];
    const float* fc2_b  = (const float*)d_in[9];
    float* out = (float*)d_out;

    // d_ws: only the activation tensor X (B*32*64^3 floats = 128 MiB), updated in place.
    float* X = (float*)d_ws;

    // Spectral stage buffers live in d_out's dead space (20 MiB of 36 MiB total).
    // All are dead before k_head/k_hard overwrite tau/du at the end.
    float2* S2 = (float2*)(out);                // 1048576 float2 =  8 MiB, floats [0, 2097152)
    float2* S3 = (float2*)(out + 2097152);      //  262144 float2 =  2 MiB
    float2* S4 = (float2*)(out + 2621440);      //  262144 float2 =  2 MiB
    float2* S5 = (float2*)(out + 3145728);      // 1048576 float2 =  8 MiB, ends at float 5242880

    k_fc0<<<4096, 256, 0, stream>>>(u, fc0_w, fc0_b, X);

    for (int l = 0; l < 4; l++) {
        k_fwd_zy<<<2048, 256, 0, stream>>>(X, S2);
        k_fwd_x<<<1024, 256, 0, stream>>>(S2, S3);
        k_specmul<<<1024, 128, 0, stream>>>(S3, spec_w, S4, l);
        k_inv_x<<<1024, 256, 0, stream>>>(S4, S5);
        k_inv_yz_pw<<<2048, 256, 0, stream>>>(S5, w_pw, b_pw, X, l, (l < 3) ? 1 : 0);
    }

    float* tau_out = out + (size_t)4 * 3 * R3;   // second output section (offset 3145728)
    k_head<<<4096, 256, 0, stream>>>(X, fc1_w, fc1_b, fc2_w, fc2_b, tau_out);
    k_hard<<<12288, 256, 0, stream>>>(u, tau_out, out);
}